// Round 7
// baseline (189.459 us; speedup 1.0000x reference)
//
#include <hip/hip_runtime.h>
#include <math.h>
#include <stdint.h>

// DictNet: out = sparsity(C) + h2(class-pair mean dists) + h1(group mean dists)/beta
// 5 launches:
//  prep   : xT = bf16(x^T) (K-padded) | sort (count/prefix/scatter/inv/tile-prefix)
//  lyhat  : fused  partial[s] = (bf16(D_strip . C)) @ x  -- D streamed ONCE, L never
//           materialized to HBM; B-frags direct from L2-resident xT
//  reduce : yh = x - sum_s partial[s]; fused gather -> ypb (bf16) + row norms
//  classh1: per-class MFMA Gram dist sums (triangular tiles) | h1 groups
//  final  : scalar assembly

#define TB 256
#define NSEG 4
#define KS 768  // K-segment length (mult of 32; 4*768 >= 3000)

using short8 = __attribute__((ext_vector_type(8))) short;
using f32x4  = __attribute__((ext_vector_type(4))) float;

__device__ inline short f2bf(float f) {
  union { float f; unsigned u; } v; v.f = f;
  unsigned r = v.u + 0x7FFF + ((v.u >> 16) & 1);  // RNE
  return (short)(r >> 16);
}

// ---- prep: xT transpose tiles + one sort block ----
__global__ __launch_bounds__(TB) void k_prep(
    const float* __restrict__ x, const int* __restrict__ y,
    const int* __restrict__ mask, short* __restrict__ xT,
    int* __restrict__ perm, int* __restrict__ inv, int* __restrict__ cnt,
    int* __restrict__ start, int* __restrict__ tstart,
    float* __restrict__ S, float* __restrict__ h1,
    int N, int d, int KP, int nbX) {
  const int b = blockIdx.x;
  const int t = threadIdx.x;
  if (b < nbX) {
    __shared__ float tile[32][33];
    const int nbx = d >> 5;
    const int r0 = (b / nbx) * 32, c0 = (b % nbx) * 32;
    const int tx = t & 31, ty = t >> 5;  // 32 x 8
#pragma unroll
    for (int i = 0; i < 4; ++i) {
      int rr = r0 + ty + i * 8;
      tile[ty + i * 8][tx] = (rr < N) ? x[(size_t)rr * d + c0 + tx] : 0.f;
    }
    __syncthreads();
    if (r0 + tx < N) {
#pragma unroll
      for (int i = 0; i < 4; ++i) {
        int c = c0 + ty + i * 8;
        xT[(size_t)c * KP + r0 + tx] = f2bf(tile[tx][ty + i * 8]);
      }
    }
  } else {
    __shared__ int lcnt[8], lcur[8], lstart[8], ltile[8];
    if (t < 8) lcnt[t] = 0;
    if (t < 7) S[t] = 0.f;
    if (t == 0) h1[0] = 0.f;
    __syncthreads();
    for (int n = t; n < N; n += TB) {
      inv[n] = -1;
      if (mask[n] != 0) atomicAdd(&lcnt[y[n]], 1);
    }
    __syncthreads();
    if (t == 0) {
      int s = 0;
      for (int c = 0; c < 7; ++c) { lstart[c] = s; lcur[c] = s; s += lcnt[c]; }
      lstart[7] = s;
      int tt = 0;
      for (int c = 0; c < 7; ++c) {
        int nb = (lcnt[c] + 63) >> 6;
        ltile[c] = tt; tt += nb * (nb + 1) / 2;
      }
      ltile[7] = tt;
    }
    __syncthreads();
    for (int n = t; n < N; n += TB)
      if (mask[n] != 0) { int p = atomicAdd(&lcur[y[n]], 1); perm[p] = n; }
    __syncthreads();
    const int tot = lstart[7];
    for (int p = t; p < tot; p += TB) inv[perm[p]] = p;
    if (t < 8) {
      start[t] = lstart[t];
      cnt[t] = (t < 7) ? lcnt[t] : 0;
      tstart[t] = ltile[t];
    }
  }
}

// ---- fused L-compute + GEMM ----
// blockIdx = panel*NSEG + s. Block: 32 rows x 512 cols, K in [s*KS, s*KS+KS).
// D strip streamed once into registers -> L bf16 into dbuf LDS -> MFMA vs
// B-frags read directly from xT (L2-resident per-XCD slice).
__global__ __launch_bounds__(512) void k_lyhat(
    const float* __restrict__ D, const float* __restrict__ Cv,
    const short* __restrict__ xT, float* __restrict__ partial,
    int N, int d, int KP) {
  __shared__ short As[2][32][40];
  const int s = blockIdx.x & (NSEG - 1);
  const int panel = blockIdx.x / NSEG;
  const int r0 = panel * 32;
  const int ks0 = s * KS;
  const int klim = (N < ks0 + KS) ? N : (ks0 + KS);
  const int t = threadIdx.x;
  const int wid = t >> 6, lane = t & 63;
  const int colw = wid * 64;                 // wave's 64-col group
  const int fr = lane & 15, fq = lane >> 4;
  const int lr = t >> 4, lk = (t & 15) * 2;  // L-compute: row, k-offset (2 k's)
  const int grow = r0 + lr;

  float cf[14];
#pragma unroll
  for (int f = 0; f < 14; ++f) cf[f] = Cv[f];

  f32x4 acc[2][4] = {};
  float4 dv[7];
  {  // prologue: D regs for kk=0 (28 floats = 112B contiguous, 16B-aligned: k even)
    int k = ks0 + lk;
    if (grow < N && k + 2 <= klim) {
      const float4* p = (const float4*)(D + ((size_t)grow * N + k) * 14);
#pragma unroll
      for (int u = 0; u < 7; ++u) dv[u] = p[u];
    } else {
#pragma unroll
      for (int u = 0; u < 7; ++u) dv[u] = make_float4(0.f, 0.f, 0.f, 0.f);
    }
  }

  for (int kk = 0; kk < KS; kk += 32) {
    const int buf = (kk >> 5) & 1;
    float a0 = dv[0].x * cf[0];
    a0 = fmaf(dv[0].y, cf[1], a0);  a0 = fmaf(dv[0].z, cf[2], a0);
    a0 = fmaf(dv[0].w, cf[3], a0);  a0 = fmaf(dv[1].x, cf[4], a0);
    a0 = fmaf(dv[1].y, cf[5], a0);  a0 = fmaf(dv[1].z, cf[6], a0);
    a0 = fmaf(dv[1].w, cf[7], a0);  a0 = fmaf(dv[2].x, cf[8], a0);
    a0 = fmaf(dv[2].y, cf[9], a0);  a0 = fmaf(dv[2].z, cf[10], a0);
    a0 = fmaf(dv[2].w, cf[11], a0); a0 = fmaf(dv[3].x, cf[12], a0);
    a0 = fmaf(dv[3].y, cf[13], a0);
    float a1 = dv[3].z * cf[0];
    a1 = fmaf(dv[3].w, cf[1], a1);  a1 = fmaf(dv[4].x, cf[2], a1);
    a1 = fmaf(dv[4].y, cf[3], a1);  a1 = fmaf(dv[4].z, cf[4], a1);
    a1 = fmaf(dv[4].w, cf[5], a1);  a1 = fmaf(dv[5].x, cf[6], a1);
    a1 = fmaf(dv[5].y, cf[7], a1);  a1 = fmaf(dv[5].z, cf[8], a1);
    a1 = fmaf(dv[5].w, cf[9], a1);  a1 = fmaf(dv[6].x, cf[10], a1);
    a1 = fmaf(dv[6].y, cf[11], a1); a1 = fmaf(dv[6].z, cf[12], a1);
    a1 = fmaf(dv[6].w, cf[13], a1);
    short2 o; o.x = f2bf(a0); o.y = f2bf(a1);
    *(short2*)&As[buf][lr][lk] = o;
    if (kk + 32 < KS) {  // prefetch next K-step's D strip
      int k = ks0 + kk + 32 + lk;
      if (grow < N && k + 2 <= klim) {
        const float4* p = (const float4*)(D + ((size_t)grow * N + k) * 14);
#pragma unroll
        for (int u = 0; u < 7; ++u) dv[u] = p[u];
      } else {
#pragma unroll
        for (int u = 0; u < 7; ++u) dv[u] = make_float4(0.f, 0.f, 0.f, 0.f);
      }
    }
    __syncthreads();  // dbuf: single barrier per iter is sufficient
    const int kg = ks0 + kk + fq * 8;
    short8 af0 = *(const short8*)&As[buf][fr][fq * 8];
    short8 af1 = *(const short8*)&As[buf][16 + fr][fq * 8];
#pragma unroll
    for (int ni = 0; ni < 4; ++ni) {
      short8 bf = *(const short8*)(xT + (size_t)(colw + ni * 16 + fr) * KP + kg);
      acc[0][ni] = __builtin_amdgcn_mfma_f32_16x16x32_bf16(af0, bf, acc[0][ni], 0, 0, 0);
      acc[1][ni] = __builtin_amdgcn_mfma_f32_16x16x32_bf16(af1, bf, acc[1][ni], 0, 0, 0);
    }
  }
  float* pp = partial + (size_t)s * ((size_t)N * d);
#pragma unroll
  for (int mi = 0; mi < 2; ++mi) {
#pragma unroll
    for (int j = 0; j < 4; ++j) {
      int row = r0 + mi * 16 + fq * 4 + j;
      if (row >= N) continue;
#pragma unroll
      for (int ni = 0; ni < 4; ++ni) {
        int col = colw + ni * 16 + fr;
        pp[(size_t)row * d + col] = acc[mi][ni][j];
      }
    }
  }
}

// ---- reduce partials -> yh; fused gather -> ypb + sqp ----
__global__ __launch_bounds__(TB) void k_reduce(
    const float* __restrict__ x, const float* __restrict__ partial,
    const int* __restrict__ inv, float* __restrict__ yh,
    short* __restrict__ ypb, float* __restrict__ sqp, int N, int d) {
  int row = blockIdx.x * 4 + (threadIdx.x >> 6);
  if (row >= N) return;
  int lane = threadIdx.x & 63;
  const size_t nd = (size_t)N * d;
  const size_t off = (size_t)row * d + lane * 8;
  float4 a = *(const float4*)(x + off);
  float4 b = *(const float4*)(x + off + 4);
#pragma unroll
  for (int s = 0; s < NSEG; ++s) {
    float4 pa = *(const float4*)(partial + s * nd + off);
    float4 pb = *(const float4*)(partial + s * nd + off + 4);
    a.x -= pa.x; a.y -= pa.y; a.z -= pa.z; a.w -= pa.w;
    b.x -= pb.x; b.y -= pb.y; b.z -= pb.z; b.w -= pb.w;
  }
  *(float4*)(yh + off) = a;
  *(float4*)(yh + off + 4) = b;
  float sq = a.x * a.x + a.y * a.y + a.z * a.z + a.w * a.w
           + b.x * b.x + b.y * b.y + b.z * b.z + b.w * b.w;
#pragma unroll
  for (int o = 32; o > 0; o >>= 1) sq += __shfl_down(sq, o);
  int p = inv[row];
  if (p >= 0) {
    short8 oo;
    oo[0] = f2bf(a.x); oo[1] = f2bf(a.y); oo[2] = f2bf(a.z); oo[3] = f2bf(a.w);
    oo[4] = f2bf(b.x); oo[5] = f2bf(b.y); oo[6] = f2bf(b.z); oo[7] = f2bf(b.w);
    *(short8*)(ypb + (size_t)p * d + lane * 8) = oo;
    if (lane == 0) sqp[p] = sq;
  }
}

// ---- 1D grid: [0,G) h1 groups; [G, G+tri) class Gram tiles via tstart ----
__global__ __launch_bounds__(TB) void k_classh1(const short* __restrict__ ypb,
    const float* __restrict__ sqp, const int* __restrict__ start,
    const int* __restrict__ cnt, const int* __restrict__ tstart,
    const float* __restrict__ yh, const int* __restrict__ groups,
    float* __restrict__ S, float* __restrict__ h1, int d, int G) {
  __shared__ short As[2][64][40];
  __shared__ short Bs[2][64][40];
  __shared__ float wred[4];
  __shared__ float red[TB];
  const int t = threadIdx.x;
  const int b = blockIdx.x;

  if (b < G) {  // ---- h1 ----
    const int g = 7;
    const int* gi = groups + b * g;
    const int p = t >> 2, qq = t & 3;
    const int npair = g * g;
    float d2 = 0.f;
    if (p < npair) {
      const float4* A = (const float4*)(yh + (size_t)gi[p / g] * d);
      const float4* B = (const float4*)(yh + (size_t)gi[p % g] * d);
      const int per = (d / 4) / 4;
      for (int k = qq * per; k < (qq + 1) * per; ++k) {
        float4 a = A[k], b2 = B[k];
        float dx = a.x - b2.x, dy = a.y - b2.y, dz = a.z - b2.z, dw = a.w - b2.w;
        d2 += dx * dx + dy * dy + dz * dz + dw * dw;
      }
    }
    d2 += __shfl_down(d2, 2, 4);
    d2 += __shfl_down(d2, 1, 4);
    float v = (qq == 0 && p < npair) ? sqrtf(d2) : 0.f;
    red[t] = v;
    __syncthreads();
    for (int s = 128; s > 0; s >>= 1) {
      if (t < s) red[t] += red[t + s];
      __syncthreads();
    }
    if (t == 0) atomicAdd(h1, red[0] / (float)npair);
    return;
  }

  const int w = b - G;
  if (w >= tstart[7]) return;
  int c = 0;
  while (c < 6 && w >= tstart[c + 1]) ++c;
  const int n = cnt[c];
  const int base = start[c];
  const int k = w - tstart[c];
  int by = (int)((sqrtf(8.f * (float)k + 1.f) - 1.f) * 0.5f);
  while ((by + 1) * (by + 2) / 2 <= k) ++by;
  while (by * (by + 1) / 2 > k) --by;
  const int bx = k - by * (by + 1) / 2;
  const float factor = (bx < by) ? 2.f : 1.f;

  const int wid = t >> 6, lane = t & 63;
  const int wr = wid >> 1, wc = wid & 1;
  const int srow = t >> 2, skc = (t & 3) * 8;
  const int fr = lane & 15, fq = lane >> 4;
  const int ar = by * 64 + srow, br = bx * 64 + srow;
  const short* Ap = ypb + (size_t)(base + ar) * d + skc;
  const short* Bp = ypb + (size_t)(base + br) * d + skc;
  const short8 z8 = {0, 0, 0, 0, 0, 0, 0, 0};

  short8 ca[2], cb[2];
#pragma unroll
  for (int h = 0; h < 2; ++h) {
    ca[h] = (ar < n) ? *(const short8*)(Ap + h * 32) : z8;
    cb[h] = (br < n) ? *(const short8*)(Bp + h * 32) : z8;
  }
  f32x4 acc[2][2] = {};
  for (int k0 = 0; k0 < d; k0 += 64) {  // d % 64 == 0
    short8 na[2] = {z8, z8}, nb[2] = {z8, z8};
    const int k1 = k0 + 64;
    if (k1 < d) {
#pragma unroll
      for (int h = 0; h < 2; ++h) {
        if (ar < n) na[h] = *(const short8*)(Ap + k1 + h * 32);
        if (br < n) nb[h] = *(const short8*)(Bp + k1 + h * 32);
      }
    }
    __syncthreads();
    *(short8*)&As[0][srow][skc] = ca[0];
    *(short8*)&As[1][srow][skc] = ca[1];
    *(short8*)&Bs[0][srow][skc] = cb[0];
    *(short8*)&Bs[1][srow][skc] = cb[1];
    __syncthreads();
#pragma unroll
    for (int h = 0; h < 2; ++h) {
      short8 af[2], bf[2];
      af[0] = *(const short8*)&As[h][wr * 32 + fr][fq * 8];
      af[1] = *(const short8*)&As[h][wr * 32 + 16 + fr][fq * 8];
      bf[0] = *(const short8*)&Bs[h][wc * 32 + fr][fq * 8];
      bf[1] = *(const short8*)&Bs[h][wc * 32 + 16 + fr][fq * 8];
#pragma unroll
      for (int mi = 0; mi < 2; ++mi)
#pragma unroll
        for (int ni = 0; ni < 2; ++ni)
          acc[mi][ni] = __builtin_amdgcn_mfma_f32_16x16x32_bf16(
              af[mi], bf[ni], acc[mi][ni], 0, 0, 0);
    }
    ca[0] = na[0]; ca[1] = na[1]; cb[0] = nb[0]; cb[1] = nb[1];
  }
  float sum = 0.f;
#pragma unroll
  for (int mi = 0; mi < 2; ++mi) {
#pragma unroll
    for (int j = 0; j < 4; ++j) {
      int ri = by * 64 + wr * 32 + mi * 16 + fq * 4 + j;
      if (ri >= n) continue;
      float si = sqp[base + ri];
#pragma unroll
      for (int ni = 0; ni < 2; ++ni) {
        int cj = bx * 64 + wc * 32 + ni * 16 + fr;
        if (cj >= n) continue;
        float d2 = si + sqp[base + cj] - 2.f * acc[mi][ni][j];
        sum += sqrtf(fmaxf(d2, 0.f));
      }
    }
  }
#pragma unroll
  for (int off = 32; off > 0; off >>= 1) sum += __shfl_down(sum, off);
  if (lane == 0) wred[wid] = sum;
  __syncthreads();
  if (t == 0)
    atomicAdd(&S[c], factor * (wred[0] + wred[1] + wred[2] + wred[3]));
}

__global__ void k_final(const float* __restrict__ C, int F,
    const float* __restrict__ S, const int* __restrict__ cnt,
    const float* __restrict__ h1, float* __restrict__ out, float beta) {
  float l1 = 0.f, l2 = 0.f;
  for (int f = 0; f < F; ++f) { float v = C[f]; l1 += fabsf(v); l2 += v * v; }
  l2 = sqrtf(l2);
  float dims = sqrtf((float)F);
  float sp = (dims - l1 / l2) / (dims - 1.f);
  float h2 = 0.f;
  for (int c = 0; c < 7; ++c) {
    if (cnt[c] > 0) { float cc = (float)cnt[c]; h2 += S[c] / (cc * cc); }
  }
  out[0] = sp + h2 - h1[0] / beta;
}

extern "C" void kernel_launch(void* const* d_in, const int* in_sizes, int n_in,
                              void* d_out, int out_size, void* d_ws, size_t ws_size,
                              hipStream_t stream) {
  const float* D = (const float*)d_in[0];
  const float* C = (const float*)d_in[1];
  const float* x = (const float*)d_in[2];
  const int* y = (const int*)d_in[3];
  const int* mask = (const int*)d_in[4];  // bool arrives widened to int32
  const int* groups = (const int*)d_in[5];
  float* out = (float*)d_out;

  const int N = in_sizes[3];            // 3000
  const int F = in_sizes[1];            // 14
  const int d = in_sizes[2] / N;        // 512
  const int G = in_sizes[5] / 7;        // 200 groups of g=7
  const int KP = NSEG * KS;             // 3072 (xT k-stride, padded)

  // workspace layout
  float* ws = (float*)d_ws;
  float* yh      = ws;                            // N*d
  float* partial = yh + (size_t)N * d;            // NSEG*N*d
  float* sqp     = partial + (size_t)NSEG * N * d;  // N
  float* S       = sqp + N;                       // 8
  float* h1      = S + 8;                         // 8
  int* perm   = (int*)(h1 + 8);                   // N
  int* inv    = perm + N;                         // N
  int* cnt    = inv + N;                          // 8
  int* start  = cnt + 8;                          // 8
  int* tstart = start + 8;                        // 8
  short* xT  = (short*)(((uintptr_t)(tstart + 8) + 15) & ~(uintptr_t)15);  // d*KP
  short* ypb = xT + (size_t)d * KP;               // N*d

  const int nbX = (d / 32) * ((N + 31) / 32);
  k_prep<<<dim3(nbX + 1), TB, 0, stream>>>(x, y, mask, xT, perm, inv, cnt,
                                           start, tstart, S, h1, N, d, KP, nbX);
  {
    int panels = (N + 31) / 32;
    k_lyhat<<<dim3(panels * NSEG), 512, 0, stream>>>(D, C, xT, partial, N, d, KP);
  }
  k_reduce<<<dim3((N + 3) / 4), TB, 0, stream>>>(x, partial, inv, yh, ypb, sqp,
                                                 N, d);
  {
    int NB = (N + 63) / 64;
    int nbT = NB * (NB + 1) / 2;
    k_classh1<<<dim3(G + nbT), TB, 0, stream>>>(ypb, sqp, start, cnt, tstart,
                                                yh, groups, S, h1, d, G);
  }
  k_final<<<1, 1, 0, stream>>>(C, F, S, cnt, h1, out, (float)G / 7.0f);
}